// Round 1
// baseline (3056.800 us; speedup 1.0000x reference)
//
#include <hip/hip_runtime.h>
#include <hip/hip_bf16.h>

#define T_N 50000
#define N_N 5000
#define E_N 800000
#define FIN 4652
#define KP1 4672     // FIN padded to multiple of 32
#define DIM 256

typedef __bf16 bf16;
typedef __bf16 bf16x8 __attribute__((ext_vector_type(8)));
typedef float f32x4 __attribute__((ext_vector_type(4)));

// ---------------- weight prep: W[K][256] fp32 -> Wt[256][Kpad] bf16 (zero-pad K tail)
__global__ void prep_w_k(const float* __restrict__ W, bf16* __restrict__ Wt,
                         int K, int Kpad) {
  int k = blockIdx.x;      // [0, Kpad)
  int n = threadIdx.x;     // [0, 256)
  float v = (k < K) ? W[(size_t)k * DIM + n] : 0.f;
  Wt[(size_t)n * Kpad + k] = (bf16)v;
}

// ---------------- histogram / dinv / scan / scatter (counting sort by bin)
__global__ void hist_k(const int* __restrict__ bins, int* __restrict__ cnt, int n) {
  int i = blockIdx.x * 256 + threadIdx.x;
  if (i < n) atomicAdd(&cnt[bins[i]], 1);
}

__global__ void dinv_k(const int* __restrict__ cnt, float* __restrict__ dinv, int n) {
  int i = blockIdx.x * 256 + threadIdx.x;
  if (i < n) dinv[i] = rsqrtf((float)(cnt[i] + 1));   // +1 self-loop; always >0
}

// single-block exclusive scan; writes offsets and a cursor copy for the scatter
__global__ void scan_k(const int* __restrict__ cnt, int* __restrict__ offs,
                       int* __restrict__ curs, int n) {
  __shared__ int wsum[16];
  __shared__ int carry_s;
  int tid = threadIdx.x, wv = tid >> 6, ln = tid & 63;
  if (tid == 0) carry_s = 0;
  __syncthreads();
  for (int base = 0; base < n; base += 1024) {
    int i = base + tid;
    int v = (i < n) ? cnt[i] : 0;
    int s = v;                                  // inclusive wave scan
#pragma unroll
    for (int off = 1; off < 64; off <<= 1) {
      int t = __shfl_up(s, off);
      if (ln >= off) s += t;
    }
    if (ln == 63) wsum[wv] = s;
    __syncthreads();
    if (wv == 0) {                              // scan the 16 wave sums
      int w = (ln < 16) ? wsum[ln] : 0;
#pragma unroll
      for (int off = 1; off < 16; off <<= 1) {
        int t = __shfl_up(w, off);
        if (ln >= off) w += t;
      }
      if (ln < 16) wsum[ln] = w;
    }
    __syncthreads();
    int woff = (wv == 0) ? 0 : wsum[wv - 1];
    int total = wsum[15];
    int excl = carry_s + woff + (s - v);
    if (i < n) { offs[i] = excl; curs[i] = excl; }
    __syncthreads();                            // everyone has read carry_s/total
    if (tid == 0) carry_s += total;
    __syncthreads();
  }
}

// place item payload (or its own index) into its bin's segment
__global__ void scatter_k(const int* __restrict__ bins, const int* __restrict__ payload,
                          int* __restrict__ curs, int* __restrict__ out, int n) {
  int i = blockIdx.x * 256 + threadIdx.x;
  if (i < n) {
    int p = atomicAdd(&curs[bins[i]], 1);
    out[p] = payload ? payload[i] : i;
  }
}

// ---------------- GCN edge aggregation (sorted-by-dst, no float atomics)
// out HC[i, col_off + d] = relu( bias[d] + P[i,d]*dinv[i]^2
//                                + sum_e P[src_e, d]*dinv[src_e]*dinv[i] )
__global__ void gcn_agg_k(const bf16* __restrict__ P, const int* __restrict__ offs,
                          const int* __restrict__ cnt, const int* __restrict__ ssrc,
                          const float* __restrict__ dinv, const float* __restrict__ bias,
                          bf16* __restrict__ HC, int col_off) {
  int i = blockIdx.x, d = threadIdx.x;   // 256 threads = 256 dims
  float di = dinv[i];
  float acc = (float)P[(size_t)i * DIM + d] * di * di;
  int s0 = offs[i], e0 = s0 + cnt[i];
  for (int e = s0; e < e0; ++e) {
    int s = ssrc[e];
    acc += (float)P[(size_t)s * DIM + d] * (dinv[s] * di);
  }
  float v = acc + bias[d];
  HC[(size_t)i * 512 + col_off + d] = (bf16)fmaxf(v, 0.f);
}

// ---------------- scatter-mean into RC[n, col_off + d]
__global__ void mean_agg_k(const bf16* __restrict__ Hf, const int* __restrict__ offs,
                           const int* __restrict__ cnt, const int* __restrict__ ids,
                           bf16* __restrict__ RC, int col_off) {
  int nb = blockIdx.x, d = threadIdx.x;
  int s0 = offs[nb], c = cnt[nb];
  float acc = 0.f;
  for (int e = s0; e < s0 + c; ++e) {
    int t = ids[e];
    acc += (float)Hf[(size_t)t * DIM + d];
  }
  float denom = (c > 0) ? (float)c : 1.f;
  RC[(size_t)nb * 512 + col_off + d] = (bf16)(acc / denom);
}

// ---------------- MFMA GEMM, A bf16 [M,K] row-major, Wt bf16 [256][K], C bf16 [M,256]
// 256 threads = 4 waves; block tile 64x256; wave tile 64x64 = 4x4 16x16 frags; BK=32
#define LDA 40   // LDS row pad (elements) to spread banks

__global__ __launch_bounds__(256) void gemm_b_k(
    const bf16* __restrict__ A, const bf16* __restrict__ Wt,
    const float* __restrict__ bias, bf16* __restrict__ C,
    int M, int K, int relu) {
  __shared__ __align__(16) bf16 As[64 * LDA];
  __shared__ __align__(16) bf16 Bs[256 * LDA];
  int tid = threadIdx.x;
  int wv = tid >> 6, ln = tid & 63;
  int q = ln >> 4, r16 = ln & 15;
  int bm = blockIdx.x * 64;
  int ar = tid >> 2, acol = (tid & 3) * 8;      // A staging: 8 bf16/thread
  int arow = bm + ar; if (arow > M - 1) arow = M - 1;
  const bf16* Ap = A + (size_t)arow * K + acol;
  const bf16* Bp = Wt + (size_t)tid * K;        // B staging: row n = tid, 32 bf16
  f32x4 acc[4][4];
#pragma unroll
  for (int i = 0; i < 4; i++)
#pragma unroll
    for (int j = 0; j < 4; j++) acc[i][j] = f32x4{0.f, 0.f, 0.f, 0.f};

  for (int k0 = 0; k0 < K; k0 += 32) {
    __syncthreads();
    bf16x8 av = *(const bf16x8*)(Ap + k0);
    const bf16* bsrc = Bp + k0;
    bf16x8 b0 = *(const bf16x8*)(bsrc);
    bf16x8 b1 = *(const bf16x8*)(bsrc + 8);
    bf16x8 b2 = *(const bf16x8*)(bsrc + 16);
    bf16x8 b3 = *(const bf16x8*)(bsrc + 24);
    *(bf16x8*)&As[ar * LDA + acol] = av;
    bf16* bd = &Bs[tid * LDA];
    *(bf16x8*)(bd) = b0;       *(bf16x8*)(bd + 8) = b1;
    *(bf16x8*)(bd + 16) = b2;  *(bf16x8*)(bd + 24) = b3;
    __syncthreads();
    bf16x8 af[4], bfv[4];
#pragma unroll
    for (int mi = 0; mi < 4; mi++)
      af[mi] = *(const bf16x8*)&As[(mi * 16 + r16) * LDA + q * 8];
#pragma unroll
    for (int ni = 0; ni < 4; ni++)
      bfv[ni] = *(const bf16x8*)&Bs[(wv * 64 + ni * 16 + r16) * LDA + q * 8];
#pragma unroll
    for (int mi = 0; mi < 4; mi++)
#pragma unroll
      for (int ni = 0; ni < 4; ni++)
        acc[mi][ni] = __builtin_amdgcn_mfma_f32_16x16x32_bf16(af[mi], bfv[ni], acc[mi][ni], 0, 0, 0);
  }
  // epilogue: D row = q*4+rr (M-dim), col = r16 (N-dim)
#pragma unroll
  for (int ni = 0; ni < 4; ni++) {
    int ng = wv * 64 + ni * 16 + r16;
    float bv = bias ? bias[ng] : 0.f;
#pragma unroll
    for (int mi = 0; mi < 4; mi++) {
#pragma unroll
      for (int rr = 0; rr < 4; rr++) {
        int mg = bm + mi * 16 + q * 4 + rr;
        if (mg < M) {
          float v = acc[mi][ni][rr] + bv;
          if (relu) v = fmaxf(v, 0.f);
          C[(size_t)mg * DIM + ng] = (bf16)v;
        }
      }
    }
  }
}

// ---------------- GEMM1: A = x fp32 [50000,4652] converted to bf16 in staging
__global__ __launch_bounds__(256) void gemm_x_k(
    const float* __restrict__ X, const bf16* __restrict__ Wt,
    const float* __restrict__ bias, bf16* __restrict__ C) {
  __shared__ __align__(16) bf16 As[64 * LDA];
  __shared__ __align__(16) bf16 Bs[256 * LDA];
  int tid = threadIdx.x;
  int wv = tid >> 6, ln = tid & 63;
  int q = ln >> 4, r16 = ln & 15;
  int bm = blockIdx.x * 64;
  int ar = tid >> 2, acol = (tid & 3) * 8;
  int arow = bm + ar; if (arow > T_N - 1) arow = T_N - 1;
  const float* Xp = X + (size_t)arow * FIN;
  const bf16* Bp = Wt + (size_t)tid * KP1;
  f32x4 acc[4][4];
#pragma unroll
  for (int i = 0; i < 4; i++)
#pragma unroll
    for (int j = 0; j < 4; j++) acc[i][j] = f32x4{0.f, 0.f, 0.f, 0.f};

  for (int k0 = 0; k0 < KP1; k0 += 32) {
    __syncthreads();
    int kg = k0 + acol;
    float f[8];
    if (kg + 8 <= FIN) {
      float4 u0 = *(const float4*)(Xp + kg);
      float4 u1 = *(const float4*)(Xp + kg + 4);
      f[0] = u0.x; f[1] = u0.y; f[2] = u0.z; f[3] = u0.w;
      f[4] = u1.x; f[5] = u1.y; f[6] = u1.z; f[7] = u1.w;
    } else {
#pragma unroll
      for (int j = 0; j < 8; j++) f[j] = (kg + j < FIN) ? Xp[kg + j] : 0.f;
    }
    bf16x8 av;
#pragma unroll
    for (int j = 0; j < 8; j++) av[j] = (bf16)f[j];
    const bf16* bsrc = Bp + k0;
    bf16x8 b0 = *(const bf16x8*)(bsrc);
    bf16x8 b1 = *(const bf16x8*)(bsrc + 8);
    bf16x8 b2 = *(const bf16x8*)(bsrc + 16);
    bf16x8 b3 = *(const bf16x8*)(bsrc + 24);
    *(bf16x8*)&As[ar * LDA + acol] = av;
    bf16* bd = &Bs[tid * LDA];
    *(bf16x8*)(bd) = b0;       *(bf16x8*)(bd + 8) = b1;
    *(bf16x8*)(bd + 16) = b2;  *(bf16x8*)(bd + 24) = b3;
    __syncthreads();
    bf16x8 af[4], bfv[4];
#pragma unroll
    for (int mi = 0; mi < 4; mi++)
      af[mi] = *(const bf16x8*)&As[(mi * 16 + r16) * LDA + q * 8];
#pragma unroll
    for (int ni = 0; ni < 4; ni++)
      bfv[ni] = *(const bf16x8*)&Bs[(wv * 64 + ni * 16 + r16) * LDA + q * 8];
#pragma unroll
    for (int mi = 0; mi < 4; mi++)
#pragma unroll
      for (int ni = 0; ni < 4; ni++)
        acc[mi][ni] = __builtin_amdgcn_mfma_f32_16x16x32_bf16(af[mi], bfv[ni], acc[mi][ni], 0, 0, 0);
  }
#pragma unroll
  for (int ni = 0; ni < 4; ni++) {
    int ng = wv * 64 + ni * 16 + r16;
    float bv = bias[ng];
#pragma unroll
    for (int mi = 0; mi < 4; mi++) {
#pragma unroll
      for (int rr = 0; rr < 4; rr++) {
        int mg = bm + mi * 16 + q * 4 + rr;
        if (mg < T_N) {
          float v = fmaxf(acc[mi][ni][rr] + bv, 0.f);   // relu
          C[(size_t)mg * DIM + ng] = (bf16)v;
        }
      }
    }
  }
}

// ---------------- head: logits = F1 @ Wfb + bfb; log_softmax. one wave per row
__global__ void final_k(const bf16* __restrict__ F1, const float* __restrict__ Wfb,
                        const float* __restrict__ bfb, float* __restrict__ out) {
  int i = blockIdx.x, l = threadIdx.x;   // 64 threads
  float p[5] = {0.f, 0.f, 0.f, 0.f, 0.f};
  for (int k = l; k < DIM; k += 64) {
    float v = (float)F1[(size_t)i * DIM + k];
#pragma unroll
    for (int c = 0; c < 5; c++) p[c] += v * Wfb[k * 5 + c];
  }
#pragma unroll
  for (int off = 32; off > 0; off >>= 1)
#pragma unroll
    for (int c = 0; c < 5; c++) p[c] += __shfl_down(p[c], off);
  if (l == 0) {
    float z[5], m = -1e30f;
#pragma unroll
    for (int c = 0; c < 5; c++) { z[c] = p[c] + bfb[c]; m = fmaxf(m, z[c]); }
    float s = 0.f;
#pragma unroll
    for (int c = 0; c < 5; c++) s += expf(z[c] - m);
    float ls = m + logf(s);
#pragma unroll
    for (int c = 0; c < 5; c++) out[(size_t)i * 5 + c] = z[c] - ls;
  }
}

extern "C" void kernel_launch(void* const* d_in, const int* in_sizes, int n_in,
                              void* d_out, int out_size, void* d_ws, size_t ws_size,
                              hipStream_t stream) {
  (void)in_sizes; (void)out_size; (void)ws_size;
  if (n_in < 29) return;
  const float* x    = (const float*)d_in[0];
  const int* ei1    = (const int*)d_in[1];
  const int* ei2    = (const int*)d_in[2];
  const int* idx1   = (const int*)d_in[3];
  const int* idx2   = (const int*)d_in[4];
  const float* W_i1 = (const float*)d_in[5];  const float* b_i1 = (const float*)d_in[6];
  const float* W_i2 = (const float*)d_in[7];  const float* b_i2 = (const float*)d_in[8];
  const float* Wc11 = (const float*)d_in[9];  const float* bc11 = (const float*)d_in[10];
  const float* Wc12 = (const float*)d_in[11]; const float* bc12 = (const float*)d_in[12];
  const float* Wc21 = (const float*)d_in[13]; const float* bc21 = (const float*)d_in[14];
  const float* Wc22 = (const float*)d_in[15]; const float* bc22 = (const float*)d_in[16];
  const float* Wm1a = (const float*)d_in[17]; const float* bm1a = (const float*)d_in[18];
  const float* Wm1b = (const float*)d_in[19]; const float* bm1b = (const float*)d_in[20];
  const float* Wm2a = (const float*)d_in[21]; const float* bm2a = (const float*)d_in[22];
  const float* Wm2b = (const float*)d_in[23]; const float* bm2b = (const float*)d_in[24];
  const float* Wfa  = (const float*)d_in[25]; const float* bfa  = (const float*)d_in[26];
  const float* Wfb  = (const float*)d_in[27]; const float* bfb  = (const float*)d_in[28];

  char* base = (char*)d_ws;
  size_t off = 0;
  auto alloc = [&](size_t bytes) -> void* {
    off = (off + 255) & ~(size_t)255;
    void* p = base + off;
    off += bytes;
    return p;
  };

  bf16* WtI1  = (bf16*)alloc((size_t)DIM * KP1 * 2);
  bf16* WtI2  = (bf16*)alloc((size_t)DIM * 256 * 2);
  bf16* WtC11 = (bf16*)alloc((size_t)DIM * 256 * 2);
  bf16* WtC12 = (bf16*)alloc((size_t)DIM * 256 * 2);
  bf16* WtC21 = (bf16*)alloc((size_t)DIM * 256 * 2);
  bf16* WtC22 = (bf16*)alloc((size_t)DIM * 256 * 2);
  bf16* WtM1a = (bf16*)alloc((size_t)DIM * 512 * 2);
  bf16* WtM1b = (bf16*)alloc((size_t)DIM * 256 * 2);
  bf16* WtM2a = (bf16*)alloc((size_t)DIM * 512 * 2);
  bf16* WtM2b = (bf16*)alloc((size_t)DIM * 256 * 2);
  bf16* WtFa  = (bf16*)alloc((size_t)DIM * 512 * 2);

  int* cnt1   = (int*)alloc((size_t)T_N * 4);   // contiguous count region (memset)
  int* cnt2   = (int*)alloc((size_t)T_N * 4);
  int* cntN1  = (int*)alloc((size_t)N_N * 4);
  int* cntN2  = (int*)alloc((size_t)N_N * 4);
  int* offs1  = (int*)alloc((size_t)T_N * 4);
  int* curs1  = (int*)alloc((size_t)T_N * 4);
  int* offs2  = (int*)alloc((size_t)T_N * 4);
  int* curs2  = (int*)alloc((size_t)T_N * 4);
  int* offsN1 = (int*)alloc((size_t)N_N * 4);
  int* cursN1 = (int*)alloc((size_t)N_N * 4);
  int* offsN2 = (int*)alloc((size_t)N_N * 4);
  int* cursN2 = (int*)alloc((size_t)N_N * 4);
  float* dinv1 = (float*)alloc((size_t)T_N * 4);
  float* dinv2 = (float*)alloc((size_t)T_N * 4);
  int* sorted1 = (int*)alloc((size_t)E_N * 4);
  int* sorted2 = (int*)alloc((size_t)E_N * 4);
  int* sortedN1 = (int*)alloc((size_t)T_N * 4);
  int* sortedN2 = (int*)alloc((size_t)T_N * 4);
  bf16* SB0 = (bf16*)alloc((size_t)T_N * DIM * 2);   // 25.6 MB
  bf16* SB1 = (bf16*)alloc((size_t)T_N * DIM * 2);   // 25.6 MB
  bf16* SB2 = (bf16*)alloc((size_t)T_N * 512 * 2);   // 51.2 MB (concat buffer)
  bf16* RC  = (bf16*)alloc((size_t)N_N * 512 * 2);
  bf16* F1  = (bf16*)alloc((size_t)N_N * DIM * 2);
  float* out = (float*)d_out;

  // zero the count arrays (ws is poisoned 0xAA before every call)
  hipMemsetAsync(cnt1, 0, (size_t)((char*)cntN2 + (size_t)N_N * 4 - (char*)cnt1), stream);

  // weight prep (transpose + bf16 convert, pad K for i1)
  prep_w_k<<<KP1, 256, 0, stream>>>(W_i1, WtI1, FIN, KP1);
  prep_w_k<<<256, 256, 0, stream>>>(W_i2, WtI2, 256, 256);
  prep_w_k<<<256, 256, 0, stream>>>(Wc11, WtC11, 256, 256);
  prep_w_k<<<256, 256, 0, stream>>>(Wc12, WtC12, 256, 256);
  prep_w_k<<<256, 256, 0, stream>>>(Wc21, WtC21, 256, 256);
  prep_w_k<<<256, 256, 0, stream>>>(Wc22, WtC22, 256, 256);
  prep_w_k<<<512, 256, 0, stream>>>(Wm1a, WtM1a, 512, 512);
  prep_w_k<<<256, 256, 0, stream>>>(Wm1b, WtM1b, 256, 256);
  prep_w_k<<<512, 256, 0, stream>>>(Wm2a, WtM2a, 512, 512);
  prep_w_k<<<256, 256, 0, stream>>>(Wm2b, WtM2b, 256, 256);
  prep_w_k<<<512, 256, 0, stream>>>(Wfa, WtFa, 512, 512);

  // graph preprocessing: counting sort edges by dst, tuples by node index
  const int GE = (E_N + 255) / 256, GT = (T_N + 255) / 256;
  hist_k<<<GE, 256, 0, stream>>>(ei1 + E_N, cnt1, E_N);   // dst row
  hist_k<<<GE, 256, 0, stream>>>(ei2 + E_N, cnt2, E_N);
  hist_k<<<GT, 256, 0, stream>>>(idx1, cntN1, T_N);
  hist_k<<<GT, 256, 0, stream>>>(idx2, cntN2, T_N);
  dinv_k<<<GT, 256, 0, stream>>>(cnt1, dinv1, T_N);
  dinv_k<<<GT, 256, 0, stream>>>(cnt2, dinv2, T_N);
  scan_k<<<1, 1024, 0, stream>>>(cnt1, offs1, curs1, T_N);
  scan_k<<<1, 1024, 0, stream>>>(cnt2, offs2, curs2, T_N);
  scan_k<<<1, 1024, 0, stream>>>(cntN1, offsN1, cursN1, N_N);
  scan_k<<<1, 1024, 0, stream>>>(cntN2, offsN2, cursN2, N_N);
  scatter_k<<<GE, 256, 0, stream>>>(ei1 + E_N, ei1, curs1, sorted1, E_N);
  scatter_k<<<GE, 256, 0, stream>>>(ei2 + E_N, ei2, curs2, sorted2, E_N);
  scatter_k<<<GT, 256, 0, stream>>>(idx1, nullptr, cursN1, sortedN1, T_N);
  scatter_k<<<GT, 256, 0, stream>>>(idx2, nullptr, cursN2, sortedN2, T_N);

  // network
  const int GM = (T_N + 63) / 64;    // 782
  const int GMn = (N_N + 63) / 64;   // 79
  gemm_x_k<<<GM, 256, 0, stream>>>(x, WtI1, b_i1, SB0);                         // A1=relu(x@Wi1+b)
  gemm_b_k<<<GM, 256, 0, stream>>>(SB0, WtI2, b_i2, SB1, T_N, 256, 0);          // H=A1@Wi2+b
  gemm_b_k<<<GM, 256, 0, stream>>>(SB1, WtC11, nullptr, SB0, T_N, 256, 0);      // P=H@Wc11
  gcn_agg_k<<<T_N, 256, 0, stream>>>(SB0, offs1, cnt1, sorted1, dinv1, bc11, SB2, 0);
  gemm_b_k<<<GM, 256, 0, stream>>>(SB1, WtC12, nullptr, SB0, T_N, 256, 0);      // P=H@Wc12
  gcn_agg_k<<<T_N, 256, 0, stream>>>(SB0, offs2, cnt2, sorted2, dinv2, bc12, SB2, 256);
  gemm_b_k<<<GM, 256, 0, stream>>>(SB2, WtM1a, bm1a, SB1, T_N, 512, 1);         // A2=relu(HC@Wm1a+b)
  gemm_b_k<<<GM, 256, 0, stream>>>(SB1, WtM1b, bm1b, SB0, T_N, 256, 0);         // H'=A2@Wm1b+b
  gemm_b_k<<<GM, 256, 0, stream>>>(SB0, WtC21, nullptr, SB1, T_N, 256, 0);      // P=H'@Wc21
  gcn_agg_k<<<T_N, 256, 0, stream>>>(SB1, offs1, cnt1, sorted1, dinv1, bc21, SB2, 0);
  gemm_b_k<<<GM, 256, 0, stream>>>(SB0, WtC22, nullptr, SB1, T_N, 256, 0);      // P=H'@Wc22
  gcn_agg_k<<<T_N, 256, 0, stream>>>(SB1, offs2, cnt2, sorted2, dinv2, bc22, SB2, 256);
  gemm_b_k<<<GM, 256, 0, stream>>>(SB2, WtM2a, bm2a, SB0, T_N, 512, 1);         // A3=relu(HC@Wm2a+b)
  gemm_b_k<<<GM, 256, 0, stream>>>(SB0, WtM2b, bm2b, SB1, T_N, 256, 0);         // Hf=A3@Wm2b+b
  mean_agg_k<<<N_N, 256, 0, stream>>>(SB1, offsN1, cntN1, sortedN1, RC, 0);     // r1
  mean_agg_k<<<N_N, 256, 0, stream>>>(SB1, offsN2, cntN2, sortedN2, RC, 256);   // r2
  gemm_b_k<<<GMn, 256, 0, stream>>>(RC, WtFa, bfa, F1, N_N, 512, 1);            // relu(RC@Wfa+b)
  final_k<<<N_N, 64, 0, stream>>>(F1, Wfb, bfb, out);                           // logits + log_softmax
}